// Round 9
// baseline (86.301 us; speedup 1.0000x reference)
//
#include <hip/hip_runtime.h>
#include <hip/hip_bf16.h>

// VQ-VAE vector quantizer, MI355X — E-resident, wave = code-slice design.
// [k_prep]  64 blocks: emb -> swizzled fp8 E (x512) + cn=||e||^2 fp32; loss=0
// [k_fused] 256 blocks x 512thr (1/CU, 8 waves): block owns 128 hw rows of one b.
//   - stage full fp8 E (128KB) + cn (4KB) into LDS via global_load_lds w16
//   - A: lane loads 32 strided fp32, cvt fp8, ds_write 16KB A-tile; row-norms free
//   - phase B: wave w owns codes [128w,+128) x ALL 128 rows. A-frags av[8][4]
//     read ONCE into regs; per c-tile 4 bv reads feed 32 MFMAs (8 indep acc
//     chains). LDS ops/CU ~580 vs 2080; E-read redundancy 1x.
//   - argmin: in-reg fold (codes ascend) -> 16-lane butterfly -> 8-way LDS merge
//   - gather q=emb[k*] fp32 -> [B,D,H,W], one loss atomicAdd per block

typedef __attribute__((ext_vector_type(4))) float f32x4;

// workspace layout (bytes)
#define WS_E 0u          // fp8 swz [1024][128] = 131072
#define WS_C 131072u     // f32 cn[1024]        = 4096

#define LOSS_SCALE (1.25f / 4194304.0f)
#define NEG2_INV_LAMBDA (-2.0f / 512.0f)

static __device__ inline unsigned cvt4_fp8(float a, float b, float c, float d) {
    int v = __builtin_amdgcn_cvt_pk_fp8_f32(a, b, 0, false);
    v = __builtin_amdgcn_cvt_pk_fp8_f32(c, d, v, true);
    return (unsigned)v;
}

static __device__ inline void gload_lds16(const void* g, void* l) {
    __builtin_amdgcn_global_load_lds(
        (const __attribute__((address_space(1))) unsigned int*)g,
        (__attribute__((address_space(3))) unsigned int*)l, 16, 0, 0);
}

// ---------------- codebook prep ----------------
__global__ __launch_bounds__(256) void k_prep(const float* __restrict__ emb,
                                              char* __restrict__ Eb,
                                              float* __restrict__ cn,
                                              float* __restrict__ loss) {
    const int t = threadIdx.x;
    const int row = (blockIdx.x << 4) + (t >> 4), c = t & 15;
    const float4* ep = (const float4*)(emb + ((size_t)row << 7) + (c << 3));
    float4 e0 = ep[0], e1 = ep[1];
    float s = e0.x*e0.x + e0.y*e0.y + e0.z*e0.z + e0.w*e0.w
            + e1.x*e1.x + e1.y*e1.y + e1.z*e1.z + e1.w*e1.w;
#pragma unroll
    for (int m = 1; m < 16; m <<= 1) s += __shfl_xor(s, m);
    if (c == 0) cn[row] = s;
    uint2 v;
    v.x = cvt4_fp8(512.f*e0.x, 512.f*e0.y, 512.f*e0.z, 512.f*e0.w);
    v.y = cvt4_fp8(512.f*e1.x, 512.f*e1.y, 512.f*e1.z, 512.f*e1.w);
    *(uint2*)(Eb + row * 128 + ((c * 8) ^ ((row & 7) << 4))) = v;
    if (blockIdx.x == 0 && t == 0) loss[0] = 0.f;
}

// ---------------- fused: E-resident scoring + gather ----------------
// LDS: E @0 (128K) | A @131072 (16K; post-B overlay: ms/mi/win/bsum) |
//      cn @147456 (4K) | rs @151552 (32B)  = 151584 B.
__global__ __launch_bounds__(512, 1) void k_fused(const float* __restrict__ lat,
                                                  const float* __restrict__ emb,
                                                  const char* __restrict__ Eb,
                                                  const float* __restrict__ cn,
                                                  float* __restrict__ outq,
                                                  float* __restrict__ loss) {
    __shared__ __align__(16) char lds[151584];
    char*  ldsE = lds;                           // fp8 swz [1024][128]
    char*  ldsA = lds + 131072;                  // fp8 swz [128][128]
    float* ms   = (float*)(lds + 131072);        // overlay after phase B: [8][128]
    int*   mi   = (int*)  (lds + 135168);        // [8][128]
    int*   win  = (int*)  (lds + 139264);        // [128]
    float* bsum = (float*)(lds + 139776);        // [128]
    float* ldsC = (float*)(lds + 147456);        // [1024]
    float* rs   = (float*)(lds + 151552);        // [8]

    const int t = threadIdx.x, bm = blockIdx.x;  // 256 blocks
    const int lane = t & 63, w = t >> 6;         // 8 waves
    const int l15 = lane & 15, lg = lane >> 4;
    const int b = bm >> 3, hw0 = (bm & 7) << 7;  // 128 rows
    const int swz = (l15 & 7) << 4;

    // ---- stage E (128 KB) + cn (4 KB); latency hides under A build ----
#pragma unroll
    for (int i = 0; i < 16; ++i) {
        int base = i * 8192 + (w << 10);
        gload_lds16(Eb + base + lane * 16, ldsE + base);
    }
    if (w < 4) gload_lds16((const char*)cn + (w << 10) + lane * 16,
                           (char*)ldsC + (w << 10));

    // ---- A: lane loads 32 strided fp32 (row 16w+l15, d-slice lg) ----
    const float* lp = lat + ((size_t)b << 17) + hw0 + (w << 4) + l15;
    float xv[4][8];
#pragma unroll
    for (int ks = 0; ks < 4; ++ks)
#pragma unroll
        for (int j = 0; j < 8; ++j)
            xv[ks][j] = lp[(size_t)(ks * 32 + lg * 8 + j) << 10];

    float rn = 0.f;
#pragma unroll
    for (int ks = 0; ks < 4; ++ks) {
#pragma unroll
        for (int j = 0; j < 8; ++j) rn = fmaf(xv[ks][j], xv[ks][j], rn);
        unsigned lo = cvt4_fp8(xv[ks][0], xv[ks][1], xv[ks][2], xv[ks][3]);
        unsigned hi = cvt4_fp8(xv[ks][4], xv[ks][5], xv[ks][6], xv[ks][7]);
        long v = (long)(((unsigned long long)hi << 32) | lo);
        *(long*)(ldsA + ((w << 4) + l15) * 128 + ((ks * 32 + lg * 8) ^ swz)) = v;
    }
#pragma unroll
    for (int m = 1; m < 64; m <<= 1) rn += __shfl_xor(rn, m);
    if (lane == 0) rs[w] = rn;

    __syncthreads();     // E + cn staged (vmcnt), A-tile written (lgkm)

    // ---- av[8][4]: full A-tile into regs, read once ----
    long av[8][4];
#pragma unroll
    for (int m = 0; m < 8; ++m)
#pragma unroll
        for (int ks = 0; ks < 4; ++ks)
            av[m][ks] = *(const long*)(ldsA + (m * 16 + l15) * 128 +
                                       ((ks * 32 + lg * 8) ^ swz));

    // ---- phase B: wave w sweeps codes [128w,+128) over all 128 rows ----
    float run_s[8][4]; int run_i[8][4];
#pragma unroll
    for (int m = 0; m < 8; ++m)
#pragma unroll
        for (int r = 0; r < 4; ++r) { run_s[m][r] = 3.0e38f; run_i[m][r] = 0; }

#pragma unroll
    for (int c2 = 0; c2 < 8; ++c2) {
        const int kgb = (w << 7) + (c2 << 4);
        long bv[4];
#pragma unroll
        for (int ks = 0; ks < 4; ++ks)
            bv[ks] = *(const long*)(ldsE + (kgb + l15) * 128 +
                                    ((ks * 32 + lg * 8) ^ swz));
        const float cv = ldsC[kgb + l15];
        const int kg = kgb + l15;

        f32x4 acc[8];
#pragma unroll
        for (int m = 0; m < 8; ++m) acc[m] = (f32x4){0.f, 0.f, 0.f, 0.f};
#pragma unroll
        for (int ks = 0; ks < 4; ++ks)
#pragma unroll
            for (int m = 0; m < 8; ++m)
                acc[m] = __builtin_amdgcn_mfma_f32_16x16x32_fp8_fp8(av[m][ks], bv[ks], acc[m], 0, 0, 0);

#pragma unroll
        for (int m = 0; m < 8; ++m)
#pragma unroll
            for (int r = 0; r < 4; ++r) {
                float s = fmaf(NEG2_INV_LAMBDA, acc[m][r], cv);
                if (s < run_s[m][r]) { run_s[m][r] = s; run_i[m][r] = kg; }
            }
    }

    __syncthreads();     // phase B done everywhere -> ldsA overlay safe

    // ---- per-wave butterfly over 16 code-lanes, write [w][row] partials ----
#pragma unroll
    for (int m = 0; m < 8; ++m)
#pragma unroll
        for (int r = 0; r < 4; ++r) {
            float s = run_s[m][r]; int bi = run_i[m][r];
#pragma unroll
            for (int mask = 1; mask < 16; mask <<= 1) {
                float os = __shfl_xor(s, mask);
                int   oi = __shfl_xor(bi, mask);
                if (os < s || (os == s && oi < bi)) { s = os; bi = oi; }
            }
            if (l15 == 0) {
                int row = m * 16 + (lg << 2) + r;    // C row = lg*4 + reg
                ms[(w << 7) + row] = s;
                mi[(w << 7) + row] = bi;
            }
        }
    __syncthreads();

    // ---- 8-way merge per row (w ascending -> lowest-index tie-break) ----
    if (t < 128) {
        float bs = ms[t]; int bi = mi[t];
#pragma unroll
        for (int w2 = 1; w2 < 8; ++w2) {
            float s2 = ms[(w2 << 7) + t]; int i2 = mi[(w2 << 7) + t];
            if (s2 < bs || (s2 == bs && i2 < bi)) { bs = s2; bi = i2; }
        }
        win[t] = bi;
        bsum[t] = bs;
    }
    __syncthreads();

    if (w == 0) {        // loss partial: sum(min_s) + sum(x^2)
        float v = bsum[lane] + bsum[64 + lane];
#pragma unroll
        for (int m = 1; m < 64; m <<= 1) v += __shfl_xor(v, m);
        if (lane == 0)
            atomicAdd(loss, (v + rs[0] + rs[1] + rs[2] + rs[3] +
                             rs[4] + rs[5] + rs[6] + rs[7]) * LOSS_SCALE);
    }

    // ---- gather q = emb[k*] fp32, store [B,D,H,W] coalesced ----
    {
        const int rowl = t & 127, dg = t >> 7;       // 4 dgrps x 32 d
        const int bi = win[rowl];
        const float4* eg = (const float4*)(emb + ((size_t)bi << 7) + (dg << 5));
        float* ob = outq + ((size_t)b << 17) + ((size_t)(dg << 5) << 10) + hw0 + rowl;
#pragma unroll
        for (int jj = 0; jj < 8; ++jj) {
            float4 v = eg[jj];
            ob[(size_t)(jj * 4 + 0) << 10] = v.x;
            ob[(size_t)(jj * 4 + 1) << 10] = v.y;
            ob[(size_t)(jj * 4 + 2) << 10] = v.z;
            ob[(size_t)(jj * 4 + 3) << 10] = v.w;
        }
    }
}

extern "C" void kernel_launch(void* const* d_in, const int* in_sizes, int n_in,
                              void* d_out, int out_size, void* d_ws, size_t ws_size,
                              hipStream_t stream) {
    const float* lat = (const float*)d_in[0];   // [32,128,32,32]
    const float* emb = (const float*)d_in[1];   // [1024,128]
    float* out = (float*)d_out;                 // q (4194304) + vq_loss (1)
    char* ws = (char*)d_ws;
    char*  E    = ws + WS_E;
    float* cn   = (float*)(ws + WS_C);
    float* loss = out + 4194304;

    k_prep <<<64,  256, 0, stream>>>(emb, E, cn, loss);
    k_fused<<<256, 512, 0, stream>>>(lat, emb, E, cn, out, loss);
}

// Round 10
// 39.543 us; speedup vs baseline: 2.1825x; 2.1825x over previous
//
#include <hip/hip_runtime.h>
#include <hip/hip_bf16.h>

// VQ-VAE vector quantizer, MI355X — E-resident, wave = code-slice, split-M regs.
// [k_prep]  64 blocks: emb -> swizzled fp8 E (x512) + cn=||e||^2 fp32; loss=0
// [k_fused] 256 blocks x 512thr (1/CU, 8 waves): block owns 128 hw rows of one b.
//   - stage full fp8 E (128KB) + cn (4KB) into LDS via global_load_lds w16
//   - A: lane loads 32 strided fp32, cvt fp8, ds_write 16KB A-tile; row-norms free
//   - phase B: wave w owns codes [128w,+128). TWO row-halves (64 rows each):
//     av[4][4] (32 VGPR) + run[4][4] (32) + acc[4] (16) -> no spill (R9 lesson:
//     av[8][4]+run[8][4] spilled 128MB of scratch). 16 MFMA per 4 bv ds_reads.
//   - argmin: butterfly per half -> ms/mi (own LDS, no overlay) -> 8-way merge
//   - gather q=emb[k*] fp32 -> [B,D,H,W], one loss atomicAdd per block

typedef __attribute__((ext_vector_type(4))) float f32x4;

// workspace layout (bytes)
#define WS_E 0u          // fp8 swz [1024][128] = 131072
#define WS_C 131072u     // f32 cn[1024]        = 4096

#define LOSS_SCALE (1.25f / 4194304.0f)
#define NEG2_INV_LAMBDA (-2.0f / 512.0f)

static __device__ inline unsigned cvt4_fp8(float a, float b, float c, float d) {
    int v = __builtin_amdgcn_cvt_pk_fp8_f32(a, b, 0, false);
    v = __builtin_amdgcn_cvt_pk_fp8_f32(c, d, v, true);
    return (unsigned)v;
}

static __device__ inline void gload_lds16(const void* g, void* l) {
    __builtin_amdgcn_global_load_lds(
        (const __attribute__((address_space(1))) unsigned int*)g,
        (__attribute__((address_space(3))) unsigned int*)l, 16, 0, 0);
}

// ---------------- codebook prep ----------------
__global__ __launch_bounds__(256) void k_prep(const float* __restrict__ emb,
                                              char* __restrict__ Eb,
                                              float* __restrict__ cn,
                                              float* __restrict__ loss) {
    const int t = threadIdx.x;
    const int row = (blockIdx.x << 4) + (t >> 4), c = t & 15;
    const float4* ep = (const float4*)(emb + ((size_t)row << 7) + (c << 3));
    float4 e0 = ep[0], e1 = ep[1];
    float s = e0.x*e0.x + e0.y*e0.y + e0.z*e0.z + e0.w*e0.w
            + e1.x*e1.x + e1.y*e1.y + e1.z*e1.z + e1.w*e1.w;
#pragma unroll
    for (int m = 1; m < 16; m <<= 1) s += __shfl_xor(s, m);
    if (c == 0) cn[row] = s;
    uint2 v;
    v.x = cvt4_fp8(512.f*e0.x, 512.f*e0.y, 512.f*e0.z, 512.f*e0.w);
    v.y = cvt4_fp8(512.f*e1.x, 512.f*e1.y, 512.f*e1.z, 512.f*e1.w);
    *(uint2*)(Eb + row * 128 + ((c * 8) ^ ((row & 7) << 4))) = v;
    if (blockIdx.x == 0 && t == 0) loss[0] = 0.f;
}

// ---------------- fused: E-resident scoring + gather ----------------
// LDS: E @0 (128K) | A @131072 (16K) | cn @147456 (4K) | ms @151552 (4K) |
//      mi @155648 (4K) | win @159744 (512) | bsum @160256 (512) | rs @160768
//      = 160800 B  (<= 163840), 1 block/CU.
__global__ __launch_bounds__(512, 1) void k_fused(const float* __restrict__ lat,
                                                  const float* __restrict__ emb,
                                                  const char* __restrict__ Eb,
                                                  const float* __restrict__ cn,
                                                  float* __restrict__ outq,
                                                  float* __restrict__ loss) {
    __shared__ __align__(16) char lds[160800];
    char*  ldsE = lds;                           // fp8 swz [1024][128]
    char*  ldsA = lds + 131072;                  // fp8 swz [128][128]
    float* ldsC = (float*)(lds + 147456);        // [1024]
    float* ms   = (float*)(lds + 151552);        // [8][128]
    int*   mi   = (int*)  (lds + 155648);        // [8][128]
    int*   win  = (int*)  (lds + 159744);        // [128]
    float* bsum = (float*)(lds + 160256);        // [128]
    float* rs   = (float*)(lds + 160768);        // [8]

    const int t = threadIdx.x, bm = blockIdx.x;  // 256 blocks
    const int lane = t & 63, w = t >> 6;         // 8 waves
    const int l15 = lane & 15, lg = lane >> 4;
    const int b = bm >> 3, hw0 = (bm & 7) << 7;  // 128 rows
    const int swz = (l15 & 7) << 4;

    // ---- stage E (128 KB) + cn (4 KB); latency hides under A build ----
#pragma unroll
    for (int i = 0; i < 16; ++i) {
        int base = i * 8192 + (w << 10);
        gload_lds16(Eb + base + lane * 16, ldsE + base);
    }
    if (w < 4) gload_lds16((const char*)cn + (w << 10) + lane * 16,
                           (char*)ldsC + (w << 10));

    // ---- A: lane loads 32 strided fp32 (row 16w+l15, d-slice lg) ----
    const float* lp = lat + ((size_t)b << 17) + hw0 + (w << 4) + l15;
    float xv[4][8];
#pragma unroll
    for (int ks = 0; ks < 4; ++ks)
#pragma unroll
        for (int j = 0; j < 8; ++j)
            xv[ks][j] = lp[(size_t)(ks * 32 + lg * 8 + j) << 10];

    float rn = 0.f;
#pragma unroll
    for (int ks = 0; ks < 4; ++ks) {
#pragma unroll
        for (int j = 0; j < 8; ++j) rn = fmaf(xv[ks][j], xv[ks][j], rn);
        unsigned lo = cvt4_fp8(xv[ks][0], xv[ks][1], xv[ks][2], xv[ks][3]);
        unsigned hi = cvt4_fp8(xv[ks][4], xv[ks][5], xv[ks][6], xv[ks][7]);
        long v = (long)(((unsigned long long)hi << 32) | lo);
        *(long*)(ldsA + ((w << 4) + l15) * 128 + ((ks * 32 + lg * 8) ^ swz)) = v;
    }
#pragma unroll
    for (int m = 1; m < 64; m <<= 1) rn += __shfl_xor(rn, m);
    if (lane == 0) rs[w] = rn;

    __syncthreads();     // E + cn staged (vmcnt), A-tile written (lgkm)

    // ---- phase B: wave w sweeps codes [128w,+128); two 64-row halves ----
#pragma unroll
    for (int mh = 0; mh < 2; ++mh) {
        long av[4][4];
#pragma unroll
        for (int mm = 0; mm < 4; ++mm)
#pragma unroll
            for (int ks = 0; ks < 4; ++ks)
                av[mm][ks] = *(const long*)(ldsA + ((mh * 4 + mm) * 16 + l15) * 128 +
                                            ((ks * 32 + lg * 8) ^ swz));

        float run_s[4][4]; int run_i[4][4];
#pragma unroll
        for (int mm = 0; mm < 4; ++mm)
#pragma unroll
            for (int r = 0; r < 4; ++r) { run_s[mm][r] = 3.0e38f; run_i[mm][r] = 0; }

#pragma unroll
        for (int c2 = 0; c2 < 8; ++c2) {
            const int kgb = (w << 7) + (c2 << 4);
            long bv[4];
#pragma unroll
            for (int ks = 0; ks < 4; ++ks)
                bv[ks] = *(const long*)(ldsE + (kgb + l15) * 128 +
                                        ((ks * 32 + lg * 8) ^ swz));
            const float cv = ldsC[kgb + l15];
            const int kg = kgb + l15;

            f32x4 acc[4];
#pragma unroll
            for (int mm = 0; mm < 4; ++mm) acc[mm] = (f32x4){0.f, 0.f, 0.f, 0.f};
#pragma unroll
            for (int ks = 0; ks < 4; ++ks)
#pragma unroll
                for (int mm = 0; mm < 4; ++mm)
                    acc[mm] = __builtin_amdgcn_mfma_f32_16x16x32_fp8_fp8(av[mm][ks], bv[ks], acc[mm], 0, 0, 0);

#pragma unroll
            for (int mm = 0; mm < 4; ++mm)
#pragma unroll
                for (int r = 0; r < 4; ++r) {
                    float s = fmaf(NEG2_INV_LAMBDA, acc[mm][r], cv);
                    if (s < run_s[mm][r]) { run_s[mm][r] = s; run_i[mm][r] = kg; }
                }
        }

        // butterfly over 16 code-lanes; write this half's [w][row] partials
#pragma unroll
        for (int mm = 0; mm < 4; ++mm)
#pragma unroll
            for (int r = 0; r < 4; ++r) {
                float s = run_s[mm][r]; int bi = run_i[mm][r];
#pragma unroll
                for (int mask = 1; mask < 16; mask <<= 1) {
                    float os = __shfl_xor(s, mask);
                    int   oi = __shfl_xor(bi, mask);
                    if (os < s || (os == s && oi < bi)) { s = os; bi = oi; }
                }
                if (l15 == 0) {
                    int row = (mh * 4 + mm) * 16 + (lg << 2) + r;
                    ms[(w << 7) + row] = s;
                    mi[(w << 7) + row] = bi;
                }
            }
    }
    __syncthreads();

    // ---- 8-way merge per row (w ascending -> lowest-index tie-break) ----
    if (t < 128) {
        float bs = ms[t]; int bi = mi[t];
#pragma unroll
        for (int w2 = 1; w2 < 8; ++w2) {
            float s2 = ms[(w2 << 7) + t]; int i2 = mi[(w2 << 7) + t];
            if (s2 < bs || (s2 == bs && i2 < bi)) { bs = s2; bi = i2; }
        }
        win[t] = bi;
        bsum[t] = bs;
    }
    __syncthreads();

    if (w == 0) {        // loss partial: sum(min_s) + sum(x^2)
        float v = bsum[lane] + bsum[64 + lane];
#pragma unroll
        for (int m = 1; m < 64; m <<= 1) v += __shfl_xor(v, m);
        if (lane == 0)
            atomicAdd(loss, (v + rs[0] + rs[1] + rs[2] + rs[3] +
                             rs[4] + rs[5] + rs[6] + rs[7]) * LOSS_SCALE);
    }

    // ---- gather q = emb[k*] fp32, store [B,D,H,W] coalesced ----
    {
        const int rowl = t & 127, dg = t >> 7;       // 4 dgrps x 32 d
        const int bi = win[rowl];
        const float4* eg = (const float4*)(emb + ((size_t)bi << 7) + (dg << 5));
        float* ob = outq + ((size_t)b << 17) + ((size_t)(dg << 5) << 10) + hw0 + rowl;
#pragma unroll
        for (int jj = 0; jj < 8; ++jj) {
            float4 v = eg[jj];
            ob[(size_t)(jj * 4 + 0) << 10] = v.x;
            ob[(size_t)(jj * 4 + 1) << 10] = v.y;
            ob[(size_t)(jj * 4 + 2) << 10] = v.z;
            ob[(size_t)(jj * 4 + 3) << 10] = v.w;
        }
    }
}

extern "C" void kernel_launch(void* const* d_in, const int* in_sizes, int n_in,
                              void* d_out, int out_size, void* d_ws, size_t ws_size,
                              hipStream_t stream) {
    const float* lat = (const float*)d_in[0];   // [32,128,32,32]
    const float* emb = (const float*)d_in[1];   // [1024,128]
    float* out = (float*)d_out;                 // q (4194304) + vq_loss (1)
    char* ws = (char*)d_ws;
    char*  E    = ws + WS_E;
    float* cn   = (float*)(ws + WS_C);
    float* loss = out + 4194304;

    k_prep <<<64,  256, 0, stream>>>(emb, E, cn, loss);
    k_fused<<<256, 512, 0, stream>>>(lat, emb, E, cn, out, loss);
}